// Round 8
// baseline (137.316 us; speedup 1.0000x reference)
//
#include <hip/hip_runtime.h>
#include <hip/hip_bf16.h>
#include <hip/hip_cooperative_groups.h>
#include <math.h>

namespace cg = cooperative_groups;

#define HIDDEN 2048
#define NH 16
#define NKV 2
#define HD 128
#define CTX 4096
#define NL 36
#define EPS 1e-6f

#define CHUNK 128
#define NCHUNKS 32              /* CTX/CHUNK */
#define HPB 8                   /* Q heads per attn block (= one KV head) */
#define NATT 64                 /* NKV * NCHUNKS */
#define NBLK 256

/* ws layout (float offsets) */
#define WS_QRAW 0               /* 2048 */
#define WS_KRAW 2048            /* 256 */
#define WS_VRAW 2304            /* 256 */
#define WS_TAB  2560            /* cos[64], sin[64] */
#define WS_PML  2688            /* NH*NCHUNKS*2 = 1024 */
#define WS_PACC 3712            /* NH*NCHUNKS*128 = 65536 */

#define RSQRT_HD 0.08838834764831845f  /* 1/sqrt(128) */

__device__ __forceinline__ float dot4(float4 a, float4 b) {
    return a.x*b.x + a.y*b.y + a.z*b.z + a.w*b.w;
}

__global__ __launch_bounds__(256, 1) void fused_kernel(
    const float* __restrict__ x, const float* __restrict__ lnw,
    const float* __restrict__ wq, const float* __restrict__ bq,
    const float* __restrict__ wk, const float* __restrict__ bk,
    const float* __restrict__ wv, const float* __restrict__ bv,
    const float* __restrict__ wo, const float* __restrict__ kvc,
    const int* __restrict__ curpos, float* __restrict__ ws,
    float* __restrict__ out)
{
    cg::grid_group grid = cg::this_grid();
    const int t = threadIdx.x;
    const int lane = t & 63, wid = t >> 6;
    const int b = blockIdx.x;
    const int pos = curpos[0];

    __shared__ float nx[HIDDEN];
    __shared__ float redS[4];
    __shared__ float tab[128];
    __shared__ float kf[HD];
    __shared__ float qr[HPB][HD];
    __shared__ float sc[HPB][CHUNK];
    __shared__ float ctxh[8][HPB][HD];
    __shared__ float ctx2[HIDDEN];

    // =============== Phase A: RMSNorm + fused QKV matvec ==================
    // waves 0,1: 3 rows each (2 q + 1 kv); waves 2,3: 2 q rows.
    const int nrows = (wid < 2) ? 3 : 2;
    int Rw[3];
    Rw[0] = b * 8 + wid * 2;
    Rw[1] = Rw[0] + 1;
    Rw[2] = 2048 + b * 2 + wid;       // only used when wid<2

    const float* wr[3]; float bias[3];
    #pragma unroll
    for (int r = 0; r < 3; ++r) {
        const int R = Rw[r];
        if (R < 2048)      { wr[r] = wq + (size_t)R * HIDDEN;          bias[r] = bq[R]; }
        else if (R < 2304) { wr[r] = wk + (size_t)(R - 2048) * HIDDEN; bias[r] = bk[R - 2048]; }
        else               { wr[r] = wv + (size_t)(R - 2304) * HIDDEN; bias[r] = bv[R - 2304]; }
    }

    // issue x/lnw, then weight rows (coalesced 16B/lane)
    float4 xa = ((const float4*)x)[t * 2];
    float4 xb = ((const float4*)x)[t * 2 + 1];
    float4 la = ((const float4*)lnw)[t * 2];
    float4 lb = ((const float4*)lnw)[t * 2 + 1];
    float4 u0[8], u1[8], u2[8];
    #pragma unroll
    for (int j = 0; j < 8; ++j) u0[j] = ((const float4*)wr[0])[j * 64 + lane];
    #pragma unroll
    for (int j = 0; j < 8; ++j) u1[j] = ((const float4*)wr[1])[j * 64 + lane];
    if (wid < 2) {
        #pragma unroll
        for (int j = 0; j < 8; ++j) u2[j] = ((const float4*)wr[2])[j * 64 + lane];
    }

    // RoPE table: block 0, wave 3 (VALU work overlapping the load wait)
    if (b == 0 && wid == 3) {
        const int i = lane;
        double e = (double)i * (1.0 / 64.0);
        double invf = exp2(-19.931568569324174087 * e);   /* 1e6^-e */
        double a = (double)pos * invf;
        a -= 6.2831853071795864769 * floor(a * 0.15915494309189533577);
        float s, c;
        sincosf((float)a, &s, &c);
        ws[WS_TAB + i] = c;
        ws[WS_TAB + 64 + i] = s;
    }

    // RMSNorm
    float ss = dot4(xa, xa) + dot4(xb, xb);
    #pragma unroll
    for (int m = 32; m; m >>= 1) ss += __shfl_xor(ss, m);
    if (lane == 0) redS[wid] = ss;
    __syncthreads();
    const float inv = rsqrtf((redS[0] + redS[1] + redS[2] + redS[3]) * (1.f / HIDDEN) + EPS);
    float4 na, nb;
    na.x = xa.x * inv * la.x; na.y = xa.y * inv * la.y;
    na.z = xa.z * inv * la.z; na.w = xa.w * inv * la.w;
    nb.x = xb.x * inv * lb.x; nb.y = xb.y * inv * lb.y;
    nb.z = xb.z * inv * lb.z; nb.w = xb.w * inv * lb.w;
    ((float4*)nx)[t * 2] = na;
    ((float4*)nx)[t * 2 + 1] = nb;
    __syncthreads();

    // dots
    const float4* nx4 = (const float4*)nx;
    float acc[3] = {0.f, 0.f, 0.f};
    #pragma unroll
    for (int j = 0; j < 8; ++j) {
        float4 n = nx4[j * 64 + lane];
        acc[0] += dot4(u0[j], n);
        acc[1] += dot4(u1[j], n);
        if (wid < 2) acc[2] += dot4(u2[j], n);
    }
    #pragma unroll
    for (int r = 0; r < 3; ++r)
        #pragma unroll
        for (int m = 32; m; m >>= 1) acc[r] += __shfl_xor(acc[r], m);
    if (lane == 0) {
        ws[Rw[0]] = acc[0] + bias[0];
        ws[Rw[1]] = acc[1] + bias[1];
        if (wid < 2) ws[Rw[2]] = acc[2] + bias[2];
    }

    __threadfence();
    grid.sync();

    // =============== Phase B: attention (blocks 0..63, K/V once) ==========
    const int grp = b >> 5, c = b & 31, start = c * CHUNK;
    const bool attnRole = (b < NATT) && (start <= pos);

    if (attnRole) {
        const int nvalid = min(CHUNK, pos + 1 - start);
        const int h0 = grp * HPB;
        const float* kc = kvc + (size_t)grp * CTX * HD;
        const float* vc = kvc + (size_t)(NL * NKV + grp) * CTX * HD;
        const int g16 = t >> 4, li = t & 15;
        const int half = t >> 5, q4 = t & 31;

        // (1) small ws loads first (L2-resident)
        float tabv = 0.f, krv = 0.f, krp = 0.f;
        if (t < 128) {
            tabv = ws[WS_TAB + t];
            const float* kr = ws + WS_KRAW + (size_t)grp * HD;
            krv = kr[t]; krp = kr[t ^ 64];
        }
        float qv[4], qp[4];
        #pragma unroll
        for (int i = 0; i < 4; ++i) {
            int e = t + i * 256;
            int hh = e >> 7, d = e & 127;
            const float* q = ws + WS_QRAW + (size_t)(h0 + hh) * HD;
            qv[i] = q[d]; qp[i] = q[d ^ 64];
        }
        float4 fv = ((const float4*)(ws + WS_VRAW + (size_t)grp * HD))[q4];

        // (2) batch-issue K tile then V tile
        float4 ka[8], kb[8];
        #pragma unroll
        for (int it = 0; it < 8; ++it) {
            const int pp = start + it * 16 + g16;
            const float4* kp = (const float4*)(kc + (size_t)pp * HD + li * 8);
            ka[it] = kp[0]; kb[it] = kp[1];
        }
        float4 vv[16];
        #pragma unroll
        for (int i = 0; i < 16; ++i) {
            const int pp = start + i * 8 + half;
            vv[i] = ((const float4*)(vc + (size_t)pp * HD))[q4];
        }

        // (3) RoPE into LDS (waits only on small loads)
        if (t < 128) tab[t] = tabv;
        __syncthreads();
        if (t < 128) {
            float r = (t < 64) ? -krp : krp;
            kf[t] = krv * tab[t & 63] + r * tab[64 + (t & 63)];
        }
        #pragma unroll
        for (int i = 0; i < 4; ++i) {
            int e = t + i * 256;
            int hh = e >> 7, d = e & 127;
            float r = (d < 64) ? -qp[i] : qp[i];
            qr[hh][d] = (qv[i] * tab[d & 63] + r * tab[64 + (d & 63)]) * RSQRT_HD;
        }
        __syncthreads();

        // (4) scores: two passes of 4 heads over the same K registers
        #pragma unroll
        for (int P = 0; P < 2; ++P) {
            float4 qa[4], qb[4];
            #pragma unroll
            for (int hh = 0; hh < 4; ++hh) {
                qa[hh] = *(const float4*)&qr[P * 4 + hh][li * 8];
                qb[hh] = *(const float4*)&qr[P * 4 + hh][li * 8 + 4];
            }
            #pragma unroll
            for (int it = 0; it < 8; ++it) {
                const int pl = it * 16 + g16;
                float4 A = ka[it], B = kb[it];
                if (start + pl == pos) {
                    A = *(const float4*)&kf[li * 8];
                    B = *(const float4*)&kf[li * 8 + 4];
                }
                float s0 = dot4(qa[0], A) + dot4(qb[0], B);
                float s1 = dot4(qa[1], A) + dot4(qb[1], B);
                float s2 = dot4(qa[2], A) + dot4(qb[2], B);
                float s3 = dot4(qa[3], A) + dot4(qb[3], B);
                #pragma unroll
                for (int m = 1; m < 16; m <<= 1) {
                    s0 += __shfl_xor(s0, m); s1 += __shfl_xor(s1, m);
                    s2 += __shfl_xor(s2, m); s3 += __shfl_xor(s3, m);
                }
                if (pl < nvalid && li == 0) {
                    sc[P * 4 + 0][pl] = s0; sc[P * 4 + 1][pl] = s1;
                    sc[P * 4 + 2][pl] = s2; sc[P * 4 + 3][pl] = s3;
                }
            }
        }
        #pragma unroll
        for (int i = 0; i < 4; ++i) {   // zero invalid tail
            int e = t + i * 256;
            int hh = e >> 7, pl = e & 127;
            if (pl >= nvalid) sc[hh][pl] = 0.f;
        }
        __syncthreads();

        // (5) softmax stats: wave wid -> heads wid, wid+4
        #pragma unroll
        for (int pass = 0; pass < 2; ++pass) {
            const int hh = wid + pass * 4;
            float m = -INFINITY;
            for (int pp = lane; pp < nvalid; pp += 64) m = fmaxf(m, sc[hh][pp]);
            #pragma unroll
            for (int mm = 32; mm; mm >>= 1) m = fmaxf(m, __shfl_xor(m, mm));
            float l = 0.f;
            for (int pp = lane; pp < nvalid; pp += 64) {
                float e = expf(sc[hh][pp] - m);
                sc[hh][pp] = e;
                l += e;
            }
            #pragma unroll
            for (int mm = 32; mm; mm >>= 1) l += __shfl_xor(l, mm);
            if (lane == 0) {
                ws[WS_PML + ((size_t)(h0 + hh) * NCHUNKS + c) * 2]     = m;
                ws[WS_PML + ((size_t)(h0 + hh) * NCHUNKS + c) * 2 + 1] = l;
            }
        }
        __syncthreads();

        // (6) ctx partial from register-resident V
        #pragma unroll
        for (int P = 0; P < 2; ++P) {
            float4 a[4];
            #pragma unroll
            for (int hh = 0; hh < 4; ++hh) a[hh] = make_float4(0.f, 0.f, 0.f, 0.f);
            #pragma unroll
            for (int i = 0; i < 16; ++i) {
                const int pl = i * 8 + half;
                float4 xv = (start + pl == pos) ? fv : vv[i];
                #pragma unroll
                for (int hh = 0; hh < 4; ++hh) {
                    float w = sc[P * 4 + hh][pl];
                    a[hh].x += w * xv.x; a[hh].y += w * xv.y;
                    a[hh].z += w * xv.z; a[hh].w += w * xv.w;
                }
            }
            #pragma unroll
            for (int hh = 0; hh < 4; ++hh)
                *(float4*)&ctxh[half][P * 4 + hh][q4 * 4] = a[hh];
        }
        __syncthreads();

        #pragma unroll
        for (int i = 0; i < 4; ++i) {
            int e = t + i * 256;
            int hh = e >> 7, d = e & 127;
            float s = 0.f;
            #pragma unroll
            for (int hf = 0; hf < 8; ++hf) s += ctxh[hf][hh][d];
            ws[WS_PACC + ((size_t)(h0 + hh) * NCHUNKS + c) * 128 + d] = s;
        }
    }

    // wo hoist: non-attn blocks get here immediately and stream 16 MB
    // while the 48 attn blocks compute.
    const int row0 = b * 8 + wid * 2;
    const float4* w04 = (const float4*)(wo + (size_t)row0 * HIDDEN);
    const float4* w14 = (const float4*)(wo + (size_t)(row0 + 1) * HIDDEN);
    float4 u[8], v[8];
    #pragma unroll
    for (int j = 0; j < 8; ++j) { u[j] = w04[j * 64 + lane]; v[j] = w14[j * 64 + lane]; }

    __threadfence();
    grid.sync();

    // =============== Phase C: combine + out proj + residual ===============
    {
        const int nc = pos / CHUNK + 1;
        const int h = t >> 4, sub = t & 15;
        float M = -INFINITY;
        for (int c2 = 0; c2 < nc; ++c2)
            M = fmaxf(M, ws[WS_PML + ((size_t)h * NCHUNKS + c2) * 2]);
        float L = 0.f;
        float4 acc0 = make_float4(0.f,0.f,0.f,0.f), acc1 = make_float4(0.f,0.f,0.f,0.f);
        for (int c2 = 0; c2 < nc; ++c2) {
            float mm = ws[WS_PML + ((size_t)h * NCHUNKS + c2) * 2];
            float ll = ws[WS_PML + ((size_t)h * NCHUNKS + c2) * 2 + 1];
            float w = expf(mm - M);
            L += w * ll;
            const float4* pa = (const float4*)(ws + WS_PACC + ((size_t)h * NCHUNKS + c2) * 128 + sub * 8);
            float4 p0 = pa[0], p1 = pa[1];
            acc0.x += w*p0.x; acc0.y += w*p0.y; acc0.z += w*p0.z; acc0.w += w*p0.w;
            acc1.x += w*p1.x; acc1.y += w*p1.y; acc1.z += w*p1.z; acc1.w += w*p1.w;
        }
        float invL = 1.f / L;
        acc0.x *= invL; acc0.y *= invL; acc0.z *= invL; acc0.w *= invL;
        acc1.x *= invL; acc1.y *= invL; acc1.z *= invL; acc1.w *= invL;
        *(float4*)&ctx2[h * HD + sub * 8]     = acc0;
        *(float4*)&ctx2[h * HD + sub * 8 + 4] = acc1;
    }
    __syncthreads();

    const float4* c4 = (const float4*)ctx2;
    float a0 = 0.f, a1 = 0.f;
    #pragma unroll
    for (int j = 0; j < 8; ++j) {
        float4 n = c4[j * 64 + lane];
        a0 += dot4(u[j], n);
        a1 += dot4(v[j], n);
    }
    #pragma unroll
    for (int m = 32; m; m >>= 1) { a0 += __shfl_xor(a0, m); a1 += __shfl_xor(a1, m); }
    if (lane == 0) {
        out[row0]     = x[row0]     + a0;
        out[row0 + 1] = x[row0 + 1] + a1;
    }
}

extern "C" void kernel_launch(void* const* d_in, const int* in_sizes, int n_in,
                              void* d_out, int out_size, void* d_ws, size_t ws_size,
                              hipStream_t stream)
{
    const float* hidden = (const float*)d_in[0];
    const int*   cur    = (const int*)d_in[3];
    const float* lnw    = (const float*)d_in[4];
    const float* wq     = (const float*)d_in[5];
    const float* bq     = (const float*)d_in[6];
    const float* wk     = (const float*)d_in[7];
    const float* bk     = (const float*)d_in[8];
    const float* wv     = (const float*)d_in[9];
    const float* bv     = (const float*)d_in[10];
    const float* wo     = (const float*)d_in[11];
    const float* kv     = (const float*)d_in[12];
    float* ws  = (float*)d_ws;
    float* out = (float*)d_out;

    void* args[] = { (void*)&hidden, (void*)&lnw, (void*)&wq, (void*)&bq,
                     (void*)&wk, (void*)&bk, (void*)&wv, (void*)&bv,
                     (void*)&wo, (void*)&kv, (void*)&cur, (void*)&ws,
                     (void*)&out };
    hipLaunchCooperativeKernel((void*)fused_kernel, dim3(NBLK), dim3(256),
                               args, 0, stream);
}

// Round 9
// 89.581 us; speedup vs baseline: 1.5329x; 1.5329x over previous
//
#include <hip/hip_runtime.h>
#include <hip/hip_bf16.h>
#include <math.h>

#define HIDDEN 2048
#define NH 16
#define NKV 2
#define HD 128
#define CTX 4096
#define NL 36
#define EPS 1e-6f

#define CHUNK 128
#define NCHUNKS 32              /* CTX/CHUNK */
#define HPB 8                   /* Q heads per attn block (= one KV head) */
#define NATT 64                 /* NKV * NCHUNKS producer blocks */

/* ws layout (float offsets) */
#define WS_QRAW 0               /* 2048 */
#define WS_KRAW 2048            /* 256 */
#define WS_VRAW 2304            /* 256 */
#define WS_TAB  2560            /* cos[64], sin[64] */
#define WS_PML  2688            /* NH*NCHUNKS*2 = 1024 */
#define WS_PACC 3712            /* NH*NCHUNKS*128 = 65536 */
#define WS_FLAG 69248           /* 64 flags, 32-float (128B) stride = 2048 */

#define RSQRT_HD 0.08838834764831845f  /* 1/sqrt(128) */

__device__ __forceinline__ float dot4(float4 a, float4 b) {
    return a.x*b.x + a.y*b.y + a.z*b.z + a.w*b.w;
}

// ---------------------------------------------------------------- K1: QKV
// blocks 0..319: 8 rows each (wave-per-2-rows, R2's proven scheme).
// block 320: RoPE table + zero the 64 producer flags (ordered by kernel
// boundary before K2; also clears the harness's 0xAA poison every call).
__global__ __launch_bounds__(256, 1) void qkv_kernel(
    const float* __restrict__ x, const float* __restrict__ lnw,
    const float* __restrict__ wq, const float* __restrict__ bq,
    const float* __restrict__ wk, const float* __restrict__ bk,
    const float* __restrict__ wv, const float* __restrict__ bv,
    const int* __restrict__ curpos, float* __restrict__ ws)
{
    const int t = threadIdx.x;
    const int lane = t & 63, wid = t >> 6;

    if (blockIdx.x == 320) {
        if (t < 64) {
            ((int*)(ws + WS_FLAG))[t * 32] = 0;
            double e = (double)t * (1.0 / 64.0);
            double invf = exp2(-19.931568569324174087 * e);   /* 1e6^-e */
            double a = (double)curpos[0] * invf;
            a -= 6.2831853071795864769 * floor(a * 0.15915494309189533577);
            float s, c;
            sincosf((float)a, &s, &c);
            ws[WS_TAB + t] = c;
            ws[WS_TAB + 64 + t] = s;
        }
        return;
    }

    // ---- hoist weight loads (64 VGPRs) so the HBM stream starts now
    const int R0 = blockIdx.x * 8 + wid * 2;
    const float *w0, *w1; float b0, b1; float *dst0, *dst1;
    {
        int R = R0;
        if (R < 2048)      { w0 = wq + (size_t)R * HIDDEN;            b0 = bq[R];   dst0 = ws + WS_QRAW + R; }
        else if (R < 2304) { int r = R - 2048; w0 = wk + (size_t)r * HIDDEN; b0 = bk[r]; dst0 = ws + WS_KRAW + r; }
        else               { int r = R - 2304; w0 = wv + (size_t)r * HIDDEN; b0 = bv[r]; dst0 = ws + WS_VRAW + r; }
        R = R0 + 1;
        if (R < 2048)      { w1 = wq + (size_t)R * HIDDEN;            b1 = bq[R];   dst1 = ws + WS_QRAW + R; }
        else if (R < 2304) { int r = R - 2048; w1 = wk + (size_t)r * HIDDEN; b1 = bk[r]; dst1 = ws + WS_KRAW + r; }
        else               { int r = R - 2304; w1 = wv + (size_t)r * HIDDEN; b1 = bv[r]; dst1 = ws + WS_VRAW + r; }
    }
    const float4* w04 = (const float4*)w0;
    const float4* w14 = (const float4*)w1;
    float4 u[8], v[8];
    #pragma unroll
    for (int j = 0; j < 8; ++j) { u[j] = w04[j * 64 + lane]; v[j] = w14[j * 64 + lane]; }

    // ---- RMSNorm (redundant per block; x/lnw L2/L3-resident)
    __shared__ float nx[HIDDEN];
    __shared__ float red[4];
    float4 xa = ((const float4*)x)[t * 2];
    float4 xb = ((const float4*)x)[t * 2 + 1];
    float ss = dot4(xa, xa) + dot4(xb, xb);
    #pragma unroll
    for (int m = 32; m; m >>= 1) ss += __shfl_xor(ss, m);
    if (lane == 0) red[wid] = ss;
    __syncthreads();
    float inv = rsqrtf((red[0] + red[1] + red[2] + red[3]) * (1.f / HIDDEN) + EPS);
    float4 la = ((const float4*)lnw)[t * 2];
    float4 lb = ((const float4*)lnw)[t * 2 + 1];
    float4 na, nb;
    na.x = xa.x * inv * la.x; na.y = xa.y * inv * la.y;
    na.z = xa.z * inv * la.z; na.w = xa.w * inv * la.w;
    nb.x = xb.x * inv * lb.x; nb.y = xb.y * inv * lb.y;
    nb.z = xb.z * inv * lb.z; nb.w = xb.w * inv * lb.w;
    ((float4*)nx)[t * 2] = na;
    ((float4*)nx)[t * 2 + 1] = nb;
    __syncthreads();

    // ---- dot
    const float4* nx4 = (const float4*)nx;
    float a0 = 0.f, a1 = 0.f;
    #pragma unroll
    for (int j = 0; j < 8; ++j) {
        float4 n = nx4[j * 64 + lane];
        a0 += dot4(u[j], n);
        a1 += dot4(v[j], n);
    }
    #pragma unroll
    for (int m = 32; m; m >>= 1) { a0 += __shfl_xor(a0, m); a1 += __shfl_xor(a1, m); }
    if (lane == 0) { *dst0 = a0 + b0; *dst1 = a1 + b1; }
}

// ------------------- K2: attn (producers) + flag + combine + out (all)
__global__ __launch_bounds__(256, 1) void attn_out_kernel(
    const float* __restrict__ wo, const float* __restrict__ kvc,
    const int* __restrict__ curpos, const float* __restrict__ hidden,
    float* __restrict__ ws, float* __restrict__ out)
{
    const int t = threadIdx.x;
    const int lane = t & 63, wid = t >> 6;
    const int b = blockIdx.x;
    const int pos = curpos[0];
    int* flg = (int*)(ws + WS_FLAG);

    __shared__ float tab[128];
    __shared__ float kf[HD];
    __shared__ float qr[HPB][HD];
    __shared__ float sc[HPB][CHUNK];
    __shared__ float ctxh[8][HPB][HD];
    __shared__ float ctx2[HIDDEN];

    // =============== producer phase: blocks 0..63 =========================
    if (b < NATT) {
        const int grp = b >> 5, c = b & 31, start = c * CHUNK;
        if (start <= pos) {
            const int nvalid = min(CHUNK, pos + 1 - start);
            const int h0 = grp * HPB;
            const float* kc = kvc + (size_t)grp * CTX * HD;
            const float* vc = kvc + (size_t)(NL * NKV + grp) * CTX * HD;
            const int g16 = t >> 4, li = t & 15;
            const int half = t >> 5, q4 = t & 31;

            // (1) small ws loads first (L2-resident)
            float tabv = 0.f, krv = 0.f, krp = 0.f;
            if (t < 128) {
                tabv = ws[WS_TAB + t];
                const float* kr = ws + WS_KRAW + (size_t)grp * HD;
                krv = kr[t]; krp = kr[t ^ 64];
            }
            float qv[4], qp[4];
            #pragma unroll
            for (int i = 0; i < 4; ++i) {
                int e = t + i * 256;
                int hh = e >> 7, d = e & 127;
                const float* q = ws + WS_QRAW + (size_t)(h0 + hh) * HD;
                qv[i] = q[d]; qp[i] = q[d ^ 64];
            }
            float4 fv = ((const float4*)(ws + WS_VRAW + (size_t)grp * HD))[q4];

            // (2) batch-issue K tile then V tile
            float4 ka[8], kb[8];
            #pragma unroll
            for (int it = 0; it < 8; ++it) {
                const int pp = start + it * 16 + g16;
                const float4* kp = (const float4*)(kc + (size_t)pp * HD + li * 8);
                ka[it] = kp[0]; kb[it] = kp[1];
            }
            float4 vv[16];
            #pragma unroll
            for (int i = 0; i < 16; ++i) {
                const int pp = start + i * 8 + half;
                vv[i] = ((const float4*)(vc + (size_t)pp * HD))[q4];
            }

            // (3) RoPE into LDS (waits only on small loads)
            if (t < 128) tab[t] = tabv;
            __syncthreads();
            if (t < 128) {
                float r = (t < 64) ? -krp : krp;
                kf[t] = krv * tab[t & 63] + r * tab[64 + (t & 63)];
            }
            #pragma unroll
            for (int i = 0; i < 4; ++i) {
                int e = t + i * 256;
                int hh = e >> 7, d = e & 127;
                float r = (d < 64) ? -qp[i] : qp[i];
                qr[hh][d] = (qv[i] * tab[d & 63] + r * tab[64 + (d & 63)]) * RSQRT_HD;
            }
            __syncthreads();

            // (4) scores: two passes of 4 heads over the same K registers
            #pragma unroll
            for (int P = 0; P < 2; ++P) {
                float4 qa[4], qb[4];
                #pragma unroll
                for (int hh = 0; hh < 4; ++hh) {
                    qa[hh] = *(const float4*)&qr[P * 4 + hh][li * 8];
                    qb[hh] = *(const float4*)&qr[P * 4 + hh][li * 8 + 4];
                }
                #pragma unroll
                for (int it = 0; it < 8; ++it) {
                    const int pl = it * 16 + g16;
                    float4 A = ka[it], B = kb[it];
                    if (start + pl == pos) {
                        A = *(const float4*)&kf[li * 8];
                        B = *(const float4*)&kf[li * 8 + 4];
                    }
                    float s0 = dot4(qa[0], A) + dot4(qb[0], B);
                    float s1 = dot4(qa[1], A) + dot4(qb[1], B);
                    float s2 = dot4(qa[2], A) + dot4(qb[2], B);
                    float s3 = dot4(qa[3], A) + dot4(qb[3], B);
                    #pragma unroll
                    for (int m = 1; m < 16; m <<= 1) {
                        s0 += __shfl_xor(s0, m); s1 += __shfl_xor(s1, m);
                        s2 += __shfl_xor(s2, m); s3 += __shfl_xor(s3, m);
                    }
                    if (pl < nvalid && li == 0) {
                        sc[P * 4 + 0][pl] = s0; sc[P * 4 + 1][pl] = s1;
                        sc[P * 4 + 2][pl] = s2; sc[P * 4 + 3][pl] = s3;
                    }
                }
            }
            #pragma unroll
            for (int i = 0; i < 4; ++i) {   // zero invalid tail
                int e = t + i * 256;
                int hh = e >> 7, pl = e & 127;
                if (pl >= nvalid) sc[hh][pl] = 0.f;
            }
            __syncthreads();

            // (5) softmax stats: wave wid -> heads wid, wid+4
            #pragma unroll
            for (int pass = 0; pass < 2; ++pass) {
                const int hh = wid + pass * 4;
                float m = -INFINITY;
                for (int pp = lane; pp < nvalid; pp += 64) m = fmaxf(m, sc[hh][pp]);
                #pragma unroll
                for (int mm = 32; mm; mm >>= 1) m = fmaxf(m, __shfl_xor(m, mm));
                float l = 0.f;
                for (int pp = lane; pp < nvalid; pp += 64) {
                    float e = expf(sc[hh][pp] - m);
                    sc[hh][pp] = e;
                    l += e;
                }
                #pragma unroll
                for (int mm = 32; mm; mm >>= 1) l += __shfl_xor(l, mm);
                if (lane == 0) {
                    ws[WS_PML + ((size_t)(h0 + hh) * NCHUNKS + c) * 2]     = m;
                    ws[WS_PML + ((size_t)(h0 + hh) * NCHUNKS + c) * 2 + 1] = l;
                }
            }
            __syncthreads();

            // (6) ctx partial from register-resident V
            #pragma unroll
            for (int P = 0; P < 2; ++P) {
                float4 a[4];
                #pragma unroll
                for (int hh = 0; hh < 4; ++hh) a[hh] = make_float4(0.f, 0.f, 0.f, 0.f);
                #pragma unroll
                for (int i = 0; i < 16; ++i) {
                    const int pl = i * 8 + half;
                    float4 xv = (start + pl == pos) ? fv : vv[i];
                    #pragma unroll
                    for (int hh = 0; hh < 4; ++hh) {
                        float w = sc[P * 4 + hh][pl];
                        a[hh].x += w * xv.x; a[hh].y += w * xv.y;
                        a[hh].z += w * xv.z; a[hh].w += w * xv.w;
                    }
                }
                #pragma unroll
                for (int hh = 0; hh < 4; ++hh)
                    *(float4*)&ctxh[half][P * 4 + hh][q4 * 4] = a[hh];
            }
            __syncthreads();

            #pragma unroll
            for (int i = 0; i < 4; ++i) {
                int e = t + i * 256;
                int hh = e >> 7, d = e & 127;
                float s = 0.f;
                #pragma unroll
                for (int hf = 0; hf < 8; ++hf) s += ctxh[hf][hh][d];
                ws[WS_PACC + ((size_t)(h0 + hh) * NCHUNKS + c) * 128 + d] = s;
            }
        }
        // publish: all stores visible, then release this block's flag
        __syncthreads();
        __threadfence();
        if (t == 0)
            __hip_atomic_store(&flg[b * 32], 1, __ATOMIC_RELEASE, __HIP_MEMORY_SCOPE_AGENT);
    }

    // =============== all blocks: hoist wo while producers compute =========
    const int row0 = b * 8 + wid * 2;
    const float4* w04 = (const float4*)(wo + (size_t)row0 * HIDDEN);
    const float4* w14 = (const float4*)(wo + (size_t)(row0 + 1) * HIDDEN);
    float4 u[8], v[8];
    #pragma unroll
    for (int j = 0; j < 8; ++j) { u[j] = w04[j * 64 + lane]; v[j] = w14[j * 64 + lane]; }

    // =============== wait for all 64 producer flags (read-only poll) ======
    if (wid == 0) {
        while (true) {
            int f = __hip_atomic_load(&flg[lane * 32], __ATOMIC_ACQUIRE,
                                      __HIP_MEMORY_SCOPE_AGENT);
            if (__all(f == 1)) break;
            __builtin_amdgcn_s_sleep(32);
        }
    }
    __syncthreads();
    __threadfence();

    // =============== combine (redundant per block) ========================
    {
        const int nc = pos / CHUNK + 1;
        const int h = t >> 4, sub = t & 15;
        float M = -INFINITY;
        for (int c2 = 0; c2 < nc; ++c2)
            M = fmaxf(M, ws[WS_PML + ((size_t)h * NCHUNKS + c2) * 2]);
        float L = 0.f;
        float4 acc0 = make_float4(0.f,0.f,0.f,0.f), acc1 = make_float4(0.f,0.f,0.f,0.f);
        for (int c2 = 0; c2 < nc; ++c2) {
            float mm = ws[WS_PML + ((size_t)h * NCHUNKS + c2) * 2];
            float ll = ws[WS_PML + ((size_t)h * NCHUNKS + c2) * 2 + 1];
            float w = expf(mm - M);
            L += w * ll;
            const float4* pa = (const float4*)(ws + WS_PACC + ((size_t)h * NCHUNKS + c2) * 128 + sub * 8);
            float4 p0 = pa[0], p1 = pa[1];
            acc0.x += w*p0.x; acc0.y += w*p0.y; acc0.z += w*p0.z; acc0.w += w*p0.w;
            acc1.x += w*p1.x; acc1.y += w*p1.y; acc1.z += w*p1.z; acc1.w += w*p1.w;
        }
        float invL = 1.f / L;
        acc0.x *= invL; acc0.y *= invL; acc0.z *= invL; acc0.w *= invL;
        acc1.x *= invL; acc1.y *= invL; acc1.z *= invL; acc1.w *= invL;
        *(float4*)&ctx2[h * HD + sub * 8]     = acc0;
        *(float4*)&ctx2[h * HD + sub * 8 + 4] = acc1;
    }
    __syncthreads();

    // =============== out proj + residual ==================================
    const float4* c4 = (const float4*)ctx2;
    float a0 = 0.f, a1 = 0.f;
    #pragma unroll
    for (int j = 0; j < 8; ++j) {
        float4 n = c4[j * 64 + lane];
        a0 += dot4(u[j], n);
        a1 += dot4(v[j], n);
    }
    #pragma unroll
    for (int m = 32; m; m >>= 1) { a0 += __shfl_xor(a0, m); a1 += __shfl_xor(a1, m); }
    if (lane == 0) {
        out[row0]     = hidden[row0]     + a0;
        out[row0 + 1] = hidden[row0 + 1] + a1;
    }
}

extern "C" void kernel_launch(void* const* d_in, const int* in_sizes, int n_in,
                              void* d_out, int out_size, void* d_ws, size_t ws_size,
                              hipStream_t stream)
{
    const float* hidden = (const float*)d_in[0];
    const int*   cur    = (const int*)d_in[3];
    const float* lnw    = (const float*)d_in[4];
    const float* wq     = (const float*)d_in[5];
    const float* bq     = (const float*)d_in[6];
    const float* wk     = (const float*)d_in[7];
    const float* bk     = (const float*)d_in[8];
    const float* wv     = (const float*)d_in[9];
    const float* bv     = (const float*)d_in[10];
    const float* wo     = (const float*)d_in[11];
    const float* kv     = (const float*)d_in[12];
    float* ws  = (float*)d_ws;
    float* out = (float*)d_out;

    qkv_kernel<<<dim3(321), dim3(256), 0, stream>>>(hidden, lnw, wq, bq, wk, bk, wv, bv, cur, ws);
    attn_out_kernel<<<dim3(256), dim3(256), 0, stream>>>(wo, kv, cur, hidden, ws, out);
}

// Round 10
// 45.500 us; speedup vs baseline: 3.0179x; 1.9688x over previous
//
#include <hip/hip_runtime.h>
#include <hip/hip_bf16.h>
#include <math.h>

#define HIDDEN 2048
#define NH 16
#define NKV 2
#define HD 128
#define CTX 4096
#define NL 36
#define EPS 1e-6f

#define CHUNK 64
#define NCHUNKS 64              /* CTX/CHUNK */
#define HPB 4                   /* Q heads per attn block */
#define NGRP 4                  /* NH/HPB */
#define NATT 256                /* NGRP * NCHUNKS */

/* ws layout (float offsets) */
#define WS_QRAW 0               /* 2048 */
#define WS_KRAW 2048            /* 256 */
#define WS_VRAW 2304            /* 256 */
#define WS_PML  2560            /* NH*NCHUNKS*2 = 2048 */
#define WS_PACC 4608            /* NH*NCHUNKS*128 = 131072 */

#define RSQRT_HD 0.08838834764831845f  /* 1/sqrt(128) */

__device__ __forceinline__ float dot4(float4 a, float4 b) {
    return a.x*b.x + a.y*b.y + a.z*b.z + a.w*b.w;
}

// ---------------------------------------------------------------- K1: QKV
// 320 blocks, 8 rows each, wave-per-2-rows (R2's champion scheme verbatim).
__global__ __launch_bounds__(256, 1) void qkv_kernel(
    const float* __restrict__ x, const float* __restrict__ lnw,
    const float* __restrict__ wq, const float* __restrict__ bq,
    const float* __restrict__ wk, const float* __restrict__ bk,
    const float* __restrict__ wv, const float* __restrict__ bv,
    float* __restrict__ ws)
{
    const int t = threadIdx.x;
    const int lane = t & 63, wid = t >> 6;

    // ---- hoist weight loads (64 VGPRs) so the HBM stream starts now
    const int R0 = blockIdx.x * 8 + wid * 2;
    const float *w0, *w1; float b0, b1; float *dst0, *dst1;
    {
        int R = R0;
        if (R < 2048)      { w0 = wq + (size_t)R * HIDDEN;            b0 = bq[R];   dst0 = ws + WS_QRAW + R; }
        else if (R < 2304) { int r = R - 2048; w0 = wk + (size_t)r * HIDDEN; b0 = bk[r]; dst0 = ws + WS_KRAW + r; }
        else               { int r = R - 2304; w0 = wv + (size_t)r * HIDDEN; b0 = bv[r]; dst0 = ws + WS_VRAW + r; }
        R = R0 + 1;
        if (R < 2048)      { w1 = wq + (size_t)R * HIDDEN;            b1 = bq[R];   dst1 = ws + WS_QRAW + R; }
        else if (R < 2304) { int r = R - 2048; w1 = wk + (size_t)r * HIDDEN; b1 = bk[r]; dst1 = ws + WS_KRAW + r; }
        else               { int r = R - 2304; w1 = wv + (size_t)r * HIDDEN; b1 = bv[r]; dst1 = ws + WS_VRAW + r; }
    }
    const float4* w04 = (const float4*)w0;
    const float4* w14 = (const float4*)w1;
    float4 u[8], v[8];
    #pragma unroll
    for (int j = 0; j < 8; ++j) { u[j] = w04[j * 64 + lane]; v[j] = w14[j * 64 + lane]; }

    // ---- RMSNorm (redundant per block; x/lnw L2/L3-resident)
    __shared__ float nx[HIDDEN];
    __shared__ float red[4];
    float4 xa = ((const float4*)x)[t * 2];
    float4 xb = ((const float4*)x)[t * 2 + 1];
    float ss = dot4(xa, xa) + dot4(xb, xb);
    #pragma unroll
    for (int m = 32; m; m >>= 1) ss += __shfl_xor(ss, m);
    if (lane == 0) red[wid] = ss;
    __syncthreads();
    float inv = rsqrtf((red[0] + red[1] + red[2] + red[3]) * (1.f / HIDDEN) + EPS);
    float4 la = ((const float4*)lnw)[t * 2];
    float4 lb = ((const float4*)lnw)[t * 2 + 1];
    float4 na, nb;
    na.x = xa.x * inv * la.x; na.y = xa.y * inv * la.y;
    na.z = xa.z * inv * la.z; na.w = xa.w * inv * la.w;
    nb.x = xb.x * inv * lb.x; nb.y = xb.y * inv * lb.y;
    nb.z = xb.z * inv * lb.z; nb.w = xb.w * inv * lb.w;
    ((float4*)nx)[t * 2] = na;
    ((float4*)nx)[t * 2 + 1] = nb;
    __syncthreads();

    // ---- dot
    const float4* nx4 = (const float4*)nx;
    float a0 = 0.f, a1 = 0.f;
    #pragma unroll
    for (int j = 0; j < 8; ++j) {
        float4 n = nx4[j * 64 + lane];
        a0 += dot4(u[j], n);
        a1 += dot4(v[j], n);
    }
    #pragma unroll
    for (int m = 32; m; m >>= 1) { a0 += __shfl_xor(a0, m); a1 += __shfl_xor(a1, m); }
    if (lane == 0) { *dst0 = a0 + b0; *dst1 = a1 + b1; }
}

// --------------------------------------------- K2: attn partials (256 blocks)
// HPB=4, CHUNK=64: full-GPU KV stream. Per-block fp64 RoPE table (VALU,
// overlaps outstanding K/V loads). Small ws loads issued before K/V batch.
__global__ __launch_bounds__(256, 1) void attn_kernel(
    const float* __restrict__ kvc, const int* __restrict__ curpos,
    float* __restrict__ ws)
{
    const int pos = curpos[0];
    const int grp = blockIdx.x >> 6;       /* head group 0..3 */
    const int c = blockIdx.x & 63;
    const int start = c * CHUNK;
    if (start > pos) return;
    const int nvalid = min(CHUNK, pos + 1 - start);
    const int h0 = grp * HPB;
    const int kvh = grp >> 1;              /* KV head */
    const float* kc = kvc + (size_t)kvh * CTX * HD;
    const float* vc = kvc + (size_t)(NL * NKV + kvh) * CTX * HD;

    __shared__ float tab[128];
    __shared__ float kf[HD];
    __shared__ float qr[HPB][HD];
    __shared__ float sc[HPB][CHUNK];
    __shared__ float ctxh[8][HPB][HD];

    const int t = threadIdx.x;
    const int lane = t & 63, wid = t >> 6;
    const int g16 = t >> 4, li = t & 15;
    const int half = t >> 5, q4 = t & 31;

    // ---- (1) small ws loads into registers (L2-resident)
    float krv = 0.f, krp = 0.f;
    if (t < 128) {
        const float* kr = ws + WS_KRAW + (size_t)kvh * HD;
        krv = kr[t]; krp = kr[t ^ 64];
    }
    float qv[2], qp[2];
    #pragma unroll
    for (int i = 0; i < 2; ++i) {
        int e = t + i * 256;
        int hh = e >> 7, d = e & 127;
        const float* q = ws + WS_QRAW + (size_t)(h0 + hh) * HD;
        qv[i] = q[d]; qp[i] = q[d ^ 64];
    }
    float4 fv = ((const float4*)(ws + WS_VRAW + (size_t)kvh * HD))[q4];

    // ---- (2) batch-issue K tile (4x2 float4) then V tile (8 float4)
    float4 ka[4], kb[4];
    #pragma unroll
    for (int it = 0; it < 4; ++it) {
        const int pp = start + it * 16 + g16;    // < CTX, always in-bounds
        const float4* kp = (const float4*)(kc + (size_t)pp * HD + li * 8);
        ka[it] = kp[0]; kb[it] = kp[1];
    }
    float4 vv[8];
    #pragma unroll
    for (int i = 0; i < 8; ++i) {
        const int pp = start + i * 8 + half;
        vv[i] = ((const float4*)(vc + (size_t)pp * HD))[q4];
    }

    // ---- (3) RoPE table: fp64 angle + range-reduce (pure VALU; overlaps
    //          the outstanding K/V stream)
    if (t < 64) {
        double e = (double)t * (1.0 / 64.0);
        double invf = exp2(-19.931568569324174087 * e);   /* 1e6^-e */
        double a = (double)pos * invf;
        a -= 6.2831853071795864769 * floor(a * 0.15915494309189533577);
        float s, cs;
        sincosf((float)a, &s, &cs);
        tab[t] = cs; tab[64 + t] = s;
    }
    __syncthreads();

    // ---- (4) RoPE q + fresh k into LDS (register inputs, no new loads)
    if (t < 128) {
        float r = (t < 64) ? -krp : krp;
        kf[t] = krv * tab[t & 63] + r * tab[64 + (t & 63)];
    }
    #pragma unroll
    for (int i = 0; i < 2; ++i) {
        int e = t + i * 256;
        int hh = e >> 7, d = e & 127;
        float r = (d < 64) ? -qp[i] : qp[i];
        qr[hh][d] = (qv[i] * tab[d & 63] + r * tab[64 + (d & 63)]) * RSQRT_HD;
    }
    __syncthreads();

    // ---- (5) scores: 4 heads over the K registers
    {
        float4 qa[4], qb[4];
        #pragma unroll
        for (int hh = 0; hh < 4; ++hh) {
            qa[hh] = *(const float4*)&qr[hh][li * 8];
            qb[hh] = *(const float4*)&qr[hh][li * 8 + 4];
        }
        #pragma unroll
        for (int it = 0; it < 4; ++it) {
            const int pl = it * 16 + g16;
            float4 A = ka[it], B = kb[it];
            if (start + pl == pos) {
                A = *(const float4*)&kf[li * 8];
                B = *(const float4*)&kf[li * 8 + 4];
            }
            float s0 = dot4(qa[0], A) + dot4(qb[0], B);
            float s1 = dot4(qa[1], A) + dot4(qb[1], B);
            float s2 = dot4(qa[2], A) + dot4(qb[2], B);
            float s3 = dot4(qa[3], A) + dot4(qb[3], B);
            #pragma unroll
            for (int m = 1; m < 16; m <<= 1) {
                s0 += __shfl_xor(s0, m); s1 += __shfl_xor(s1, m);
                s2 += __shfl_xor(s2, m); s3 += __shfl_xor(s3, m);
            }
            if (pl < nvalid && li == 0) {
                sc[0][pl] = s0; sc[1][pl] = s1; sc[2][pl] = s2; sc[3][pl] = s3;
            }
        }
    }
    // zero invalid tail (4 heads x 64 slots, 1/thread)
    {
        int hh = t >> 6, pl = t & 63;
        if (pl >= nvalid) sc[hh][pl] = 0.f;
    }
    __syncthreads();

    // ---- (6) softmax stats: wave wid -> head wid (one elem per lane)
    {
        float m = (lane < nvalid) ? sc[wid][lane] : -INFINITY;
        #pragma unroll
        for (int mm = 32; mm; mm >>= 1) m = fmaxf(m, __shfl_xor(m, mm));
        float l = 0.f;
        if (lane < nvalid) {
            l = expf(sc[wid][lane] - m);
            sc[wid][lane] = l;
        }
        #pragma unroll
        for (int mm = 32; mm; mm >>= 1) l += __shfl_xor(l, mm);
        if (lane == 0) {
            ws[WS_PML + ((size_t)(h0 + wid) * NCHUNKS + c) * 2]     = m;
            ws[WS_PML + ((size_t)(h0 + wid) * NCHUNKS + c) * 2 + 1] = l;
        }
    }
    __syncthreads();

    // ---- (7) ctx partial from register-resident V (8 position streams)
    {
        float4 a[4];
        #pragma unroll
        for (int hh = 0; hh < 4; ++hh) a[hh] = make_float4(0.f, 0.f, 0.f, 0.f);
        #pragma unroll
        for (int i = 0; i < 8; ++i) {
            const int pl = i * 8 + half;
            float4 xv = (start + pl == pos) ? fv : vv[i];
            #pragma unroll
            for (int hh = 0; hh < 4; ++hh) {
                float w = sc[hh][pl];
                a[hh].x += w * xv.x; a[hh].y += w * xv.y;
                a[hh].z += w * xv.z; a[hh].w += w * xv.w;
            }
        }
        #pragma unroll
        for (int hh = 0; hh < 4; ++hh)
            *(float4*)&ctxh[half][hh][q4 * 4] = a[hh];
    }
    __syncthreads();

    #pragma unroll
    for (int i = 0; i < 2; ++i) {
        int e = t + i * 256;
        int hh = e >> 7, d = e & 127;
        float s = 0.f;
        #pragma unroll
        for (int hf = 0; hf < 8; ++hf) s += ctxh[hf][hh][d];
        ws[WS_PACC + ((size_t)(h0 + hh) * NCHUNKS + c) * 128 + d] = s;
    }
}

// --------------------------- K3: combine + out proj + residual (256 blocks)
__global__ __launch_bounds__(256, 1) void out_kernel(
    const float* __restrict__ wo, const float* __restrict__ hidden,
    const float* __restrict__ ws, const int* __restrict__ curpos,
    float* __restrict__ out)
{
    const int t = threadIdx.x;
    const int lane = t & 63, wid = t >> 6;

    // hoist weight loads: 16 MB stream in flight during combine
    const int row0 = blockIdx.x * 8 + wid * 2;
    const float4* w04 = (const float4*)(wo + (size_t)row0 * HIDDEN);
    const float4* w14 = (const float4*)(wo + (size_t)(row0 + 1) * HIDDEN);
    float4 u[8], v[8];
    #pragma unroll
    for (int j = 0; j < 8; ++j) { u[j] = w04[j * 64 + lane]; v[j] = w14[j * 64 + lane]; }

    // redundant per-block combine: thread -> head t>>4, dims (t&15)*8..+7
    __shared__ float ctx[HIDDEN];
    const int pos = curpos[0];
    const int nc = pos / CHUNK + 1;
    const int h = t >> 4, sub = t & 15;
    float M = -INFINITY;
    for (int c2 = 0; c2 < nc; ++c2)
        M = fmaxf(M, ws[WS_PML + ((size_t)h * NCHUNKS + c2) * 2]);
    float L = 0.f;
    float4 acc0 = make_float4(0.f,0.f,0.f,0.f), acc1 = make_float4(0.f,0.f,0.f,0.f);
    for (int c2 = 0; c2 < nc; ++c2) {
        float mm = ws[WS_PML + ((size_t)h * NCHUNKS + c2) * 2];
        float ll = ws[WS_PML + ((size_t)h * NCHUNKS + c2) * 2 + 1];
        float w = expf(mm - M);
        L += w * ll;
        const float4* pa = (const float4*)(ws + WS_PACC + ((size_t)h * NCHUNKS + c2) * 128 + sub * 8);
        float4 p0 = pa[0], p1 = pa[1];
        acc0.x += w*p0.x; acc0.y += w*p0.y; acc0.z += w*p0.z; acc0.w += w*p0.w;
        acc1.x += w*p1.x; acc1.y += w*p1.y; acc1.z += w*p1.z; acc1.w += w*p1.w;
    }
    float invL = 1.f / L;
    acc0.x *= invL; acc0.y *= invL; acc0.z *= invL; acc0.w *= invL;
    acc1.x *= invL; acc1.y *= invL; acc1.z *= invL; acc1.w *= invL;
    *(float4*)&ctx[h * HD + sub * 8]     = acc0;
    *(float4*)&ctx[h * HD + sub * 8 + 4] = acc1;
    __syncthreads();

    const float4* c4 = (const float4*)ctx;
    float a0 = 0.f, a1 = 0.f;
    #pragma unroll
    for (int j = 0; j < 8; ++j) {
        float4 n = c4[j * 64 + lane];
        a0 += dot4(u[j], n);
        a1 += dot4(v[j], n);
    }
    #pragma unroll
    for (int m = 32; m; m >>= 1) { a0 += __shfl_xor(a0, m); a1 += __shfl_xor(a1, m); }
    if (lane == 0) {
        out[row0]     = hidden[row0]     + a0;
        out[row0 + 1] = hidden[row0 + 1] + a1;
    }
}

extern "C" void kernel_launch(void* const* d_in, const int* in_sizes, int n_in,
                              void* d_out, int out_size, void* d_ws, size_t ws_size,
                              hipStream_t stream)
{
    const float* hidden = (const float*)d_in[0];
    const int*   cur    = (const int*)d_in[3];
    const float* lnw    = (const float*)d_in[4];
    const float* wq     = (const float*)d_in[5];
    const float* bq     = (const float*)d_in[6];
    const float* wk     = (const float*)d_in[7];
    const float* bk     = (const float*)d_in[8];
    const float* wv     = (const float*)d_in[9];
    const float* bv     = (const float*)d_in[10];
    const float* wo     = (const float*)d_in[11];
    const float* kv     = (const float*)d_in[12];
    float* ws  = (float*)d_ws;
    float* out = (float*)d_out;

    qkv_kernel<<<dim3(320), dim3(256), 0, stream>>>(hidden, lnw, wq, bq, wk, bk, wv, bv, ws);
    attn_kernel<<<dim3(NATT), dim3(256), 0, stream>>>(kv, cur, ws);
    out_kernel<<<dim3(256), dim3(256), 0, stream>>>(wo, hidden, ws, cur, out);
}